// Round 2
// baseline (280.590 us; speedup 1.0000x reference)
//
#include <hip/hip_runtime.h>
#include <cstdint>
#include <cstddef>

// Problem constants
#define BATCH 8
#define CIN   512
#define COUT  512
#define RES   64
#define HW    4096      // 64*64
#define WDIM  512

typedef short bf16x8 __attribute__((ext_vector_type(8)));
typedef float f32x4  __attribute__((ext_vector_type(4)));
typedef unsigned short ushort8 __attribute__((ext_vector_type(8)));

typedef const __attribute__((address_space(1))) void* gas_ptr;
typedef __attribute__((address_space(3))) void*       las_ptr;

__device__ __forceinline__ unsigned short f2bf(float f) {
    unsigned int u = __float_as_uint(f);
    u += 0x7fffu + ((u >> 16) & 1u);   // round-to-nearest-even
    return (unsigned short)(u >> 16);
}

// ---------------------------------------------------------------------------
// Kernel 1 (fused prep): blocks 0..1023 compute style (+zero zpage);
// blocks 1024..1535 reorganize weights. The two roles are independent.
// style[b][ci] = sum_wd w[b][wd]*affine_w[ci][wd] + affine_b[ci]
// wr[tap][co][ci] = bf16(weight[co][ci][kh][kw]), tap = kh*3+kw
// ---------------------------------------------------------------------------
__global__ __launch_bounds__(256) void prep_kernel(
    const float* __restrict__ w, const float* __restrict__ aw,
    const float* __restrict__ ab, float* __restrict__ style,
    unsigned short* __restrict__ zpage,
    const float* __restrict__ wt, unsigned short* __restrict__ wr)
{
    __shared__ float buf[4608];
    int bid = blockIdx.x;
    int t = threadIdx.x;
    if (bid < 1024) {
        if (bid == 0 && t < 128) zpage[t] = 0;
        int wv = t >> 6, lane = t & 63;
        int idx = bid * 4 + wv;              // 0..4095
        int b = idx >> 9, ci = idx & 511;
        const float* wrow = w + b * WDIM;
        const float* arow = aw + (size_t)ci * WDIM;
        float s = 0.f;
#pragma unroll
        for (int i = 0; i < WDIM / 64; ++i) s += arow[lane + i * 64] * wrow[lane + i * 64];
#pragma unroll
        for (int off = 32; off; off >>= 1) s += __shfl_down(s, off);
        if (lane == 0) style[idx] = s + ab[ci];
    } else {
        int co = bid - 1024;
#pragma unroll
        for (int r = 0; r < 18; ++r) buf[r * 256 + t] = wt[(size_t)co * 4608 + r * 256 + t];
        __syncthreads();
#pragma unroll
        for (int r = 0; r < 18; ++r) {
            int idx = r * 256 + t;
            int tap = idx >> 9, ci = idx & 511;
            wr[(size_t)tap * (COUT * CIN) + co * CIN + ci] = f2bf(buf[ci * 9 + tap]);
        }
    }
}

// ---------------------------------------------------------------------------
// Kernel 2: xs[b][hw][ci] (bf16, NHWC) = bf16(x[b][ci][hw] * style[b][ci])
// 64x64 LDS-tiled transpose; 16B vectorized bf16 stores.
// ---------------------------------------------------------------------------
__global__ __launch_bounds__(256) void modtrans_kernel(
    const float* __restrict__ x, const float* __restrict__ style,
    unsigned short* __restrict__ xs)
{
    __shared__ float tile[64][65];
    int t = threadIdx.x;
    int hw0 = blockIdx.x * 64, ci0 = blockIdx.y * 64, b = blockIdx.z;
    int sub = t >> 6, lane = t & 63;
#pragma unroll
    for (int r = 0; r < 16; ++r) {
        int ci = r * 4 + sub;
        float s = style[b * CIN + ci0 + ci];
        tile[ci][lane] = x[((size_t)(b * CIN + ci0 + ci)) * HW + hw0 + lane] * s;
    }
    __syncthreads();
    int ci8 = (t & 7) * 8;
#pragma unroll
    for (int r = 0; r < 2; ++r) {
        int hw = r * 32 + (t >> 3);
        ushort8 v;
#pragma unroll
        for (int j = 0; j < 8; ++j) v[j] = f2bf(tile[ci8 + j][hw]);
        *(ushort8*)&xs[((size_t)b * HW + hw0 + hw) * CIN + ci0 + ci8] = v;
    }
}

// ---------------------------------------------------------------------------
// Kernel 3: implicit-GEMM conv, m201-style sub-phase schedule + XCD remap.
// C-tile 128(co) x 128(hw = 2 image rows). 48 phases = 3 kh x 16 ci-chunks,
// each phase = 3 kw sub-phases of {8 ds_read_b128 -> s_barrier -> 16 MFMA}.
//
// XCD remap (NEW): bid&7 = (co0-group<<1)|h-half, so each XCD's 128 blocks
// share a 1.125 MB weight slice (L2-resident, ~130x reuse) instead of all 8
// XCDs thrashing the full 4.5 MB wr stream against 4 MB L2. Weight staging
// is 75% of the 1.5 GB LDS-staging traffic -> this is the feed-BW fix.
//
// Schedule (NEW): reads-BEFORE-barrier (read latency hides under barrier
// skew; MFMA starts on a cheap lgkm wait), raw s_barrier (no implicit
// vmcnt(0) drains), stage(p+1) issued after the first MFMA cluster, ONE
// explicit vmcnt(0) per phase just before the last sub-phase barrier.
// Race audit: stage(p+1) overwrites buf[(p-1)&1]; it is issued only after
// the (p,0) barrier, and every wave lgkm-drained its buf[(p-1)&1] reads
// before reaching that barrier -> WAR is barrier-separated. reads(p,0)
// validity: every wave vmcnt(0)-drained its stage(p) portion before the
// (p-1,2) barrier -> collectively complete. Uniform control flow.
//
// Bank-conflict swizzle (unchanged): logical 16B chunk j of LDS row r lives
// at physical slot j ^ ((r>>1)&3); staging permutes the per-lane GLOBAL
// source address (LDS dest must stay base+lane*16); reads apply same xor.
// ---------------------------------------------------------------------------
__global__ __launch_bounds__(256) void conv_kernel(
    const unsigned short* __restrict__ xs,   // [8][4096][512] bf16
    const unsigned short* __restrict__ wr,   // [9][512][512]  bf16
    const float* __restrict__ bias,
    const unsigned short* __restrict__ zpage,
    float* __restrict__ y)                   // [8][512][4096] f32
{
    __shared__ __align__(16) unsigned short As[2 * 3 * 128 * 32];  // 48 KB
    __shared__ __align__(16) unsigned short Bs[2 * 2 * 66 * 32];   // 16.5 KB
    constexpr int ABUF = 3 * 128 * 32;   // ushorts per A buffer
    constexpr int BBUF = 2 * 66 * 32;    // ushorts per B buffer

    const int t   = threadIdx.x;
    const int bid = blockIdx.x;
    // XCD-keyed decode: bits[2:1]=co0-group, bit0=h-half, bits[6:3]=h-idx,
    // bits[9:7]=b.  4 * 2 * 16 * 8 = 1024 blocks.
    const int xcd = bid & 7;
    const int co0 = (xcd >> 1) * 128;
    const int h0  = (xcd & 1) * 32 + ((bid >> 3) & 15) * 2;
    const int b   = (bid >> 7) & 7;

    const int lane = t & 63;
    const int wv   = t >> 6;
    const int wm   = (wv & 1) * 64;
    const int wn   = (wv >> 1) * 64;
    const int r16  = lane & 15;
    const int quad = lane >> 4;

    // zero the pad columns (w'=0 and w'=65) of BOTH buffers (swizzle-invariant)
    {
        int bufz = t >> 7;                 // 0 or 1
        int r = t & 127;
        int d = r >> 6, c = r & 63;
        int col = (c < 32) ? 0 : 65;
        Bs[bufz * BBUF + (d * 66 + col) * 32 + (c & 31)] = 0;
    }

    f32x4 acc[4][4];
#pragma unroll
    for (int mi = 0; mi < 4; ++mi)
#pragma unroll
        for (int ni = 0; ni < 4; ++ni)
            acc[mi][ni] = (f32x4){0.f, 0.f, 0.f, 0.f};

    const unsigned short* pA[6];
    const unsigned short* pB[2];
    int sB[2];

    // (Re)compute staging pointers for a kh (at its ch=0 position).
    auto setup = [&](int kh) {
#pragma unroll
        for (int L = 0; L < 6; ++L) {
            int lin = L * 256 + t;                 // 0..1535; phys row = lin>>2
            int tap = kh * 3 + (lin >> 9);
            int q   = (lin >> 2) & 127;
            int c8  = ((lin & 3) ^ ((lin >> 3) & 3)) * 8;   // swizzled source chunk
            pA[L] = wr + (size_t)tap * (COUT * CIN) + (co0 + q) * CIN + c8;
        }
#pragma unroll
        for (int L = 0; L < 2; ++L) {
            int lin = L * 256 + t;                 // 0..511
            int dh = lin >> 8, r8 = lin & 255;
            int wc = r8 >> 2;
            int rowp = dh * 66 + 1 + wc;           // physical LDS row
            int c8 = ((r8 & 3) ^ ((rowp >> 1) & 3)) * 8;
            int hp = h0 + dh + kh - 1;
            bool ok = (unsigned)hp < 64u;
            pB[L] = ok ? xs + ((size_t)b * HW + hp * 64 + wc) * CIN + c8 : zpage;
            sB[L] = ok ? 32 : 0;
        }
    };

    // Issue one phase's 8 global_load_lds into buffer `buf`; advance pointers.
    auto stage = [&](int buf) {
        const int ab = buf * ABUF, bb = buf * BBUF;
#pragma unroll
        for (int L = 0; L < 6; ++L) {
            int lin = L * 256 + t;
            __builtin_amdgcn_global_load_lds((gas_ptr)pA[L], (las_ptr)&As[ab + lin * 8], 16, 0, 0);
            pA[L] += 32;
        }
#pragma unroll
        for (int L = 0; L < 2; ++L) {
            int lin = L * 256 + t;
            int dh = lin >> 8, r8 = lin & 255;
            __builtin_amdgcn_global_load_lds((gas_ptr)pB[L],
                (las_ptr)&Bs[bb + (dh * 66 + 1) * 32 + r8 * 8], 16, 0, 0);
            pB[L] += sB[L];
        }
    };

    // Load the 8 fragments of one kw sub-phase into af/bfv.
    auto load_frags = [&](int kw, int ab, int bb, bf16x8* af, bf16x8* bfv) {
#pragma unroll
        for (int mi = 0; mi < 4; ++mi) {
            int row = kw * 128 + wm + mi * 16 + r16;
            int ck  = quad ^ ((row >> 1) & 3);
            af[mi] = *(const bf16x8*)&As[ab + row * 32 + ck * 8];
        }
#pragma unroll
        for (int ni = 0; ni < 4; ++ni) {
            int n = wn + ni * 16 + r16;
            int dh = n >> 6, wc = n & 63;
            int row = dh * 66 + wc + kw;
            int ck  = quad ^ ((row >> 1) & 3);
            bfv[ni] = *(const bf16x8*)&Bs[bb + row * 32 + ck * 8];
        }
    };

    auto mfma16 = [&](const bf16x8* af, const bf16x8* bfv) {
        __builtin_amdgcn_s_setprio(1);
#pragma unroll
        for (int mi = 0; mi < 4; ++mi)
#pragma unroll
            for (int ni = 0; ni < 4; ++ni)
                acc[mi][ni] = __builtin_amdgcn_mfma_f32_16x16x32_bf16(
                    af[mi], bfv[ni], acc[mi][ni], 0, 0, 0);
        __builtin_amdgcn_s_setprio(0);
    };

    setup(0);
    stage(0);            // prologue: phase 0 in flight
    __syncthreads();     // vmcnt(0)+lgkmcnt(0)+barrier: buf0 valid, pads visible

    for (int p = 0; p < 48; ++p) {
        const int ab = (p & 1) * ABUF, bb = (p & 1) * BBUF;
        bf16x8 af[4], bfv[4];

        // --- sub-phase kw=0: reads before barrier hide under barrier skew ---
        load_frags(0, ab, bb, af, bfv);
        __builtin_amdgcn_s_barrier();
        mfma16(af, bfv);

        // stage(p+1) AFTER the (p,0) barrier: every wave has lgkm-drained its
        // buf[(p-1)&1] reads before that barrier -> WAR-safe overwrite.
        if (p < 47) {
            int pn = p + 1;
            if ((pn & 15) == 0) setup(pn >> 4);    // kh boundary (pn = 16, 32)
            stage(pn & 1);                         // flies across ~2 sub-phases
        }

        // --- sub-phase kw=1 ---
        load_frags(1, ab, bb, af, bfv);
        __builtin_amdgcn_s_barrier();
        mfma16(af, bfv);

        // --- sub-phase kw=2: counted drain of stage(p+1), once per phase ---
        load_frags(2, ab, bb, af, bfv);
        asm volatile("s_waitcnt vmcnt(0)" ::: "memory");
        __builtin_amdgcn_s_barrier();
        mfma16(af, bfv);
    }

    // Epilogue: C/D layout col(n)=lane&15, row(m)=quad*4+reg
#pragma unroll
    for (int mi = 0; mi < 4; ++mi) {
#pragma unroll
        for (int r = 0; r < 4; ++r) {
            int m = co0 + wm + mi * 16 + quad * 4 + r;
            float bv = bias[m];
            size_t base = ((size_t)b * COUT + m) * HW + h0 * 64;
#pragma unroll
            for (int ni = 0; ni < 4; ++ni) {
                int n = wn + ni * 16 + r16;
                y[base + n] = acc[mi][ni][r] + bv;
            }
        }
    }
}

// ---------------------------------------------------------------------------
extern "C" void kernel_launch(void* const* d_in, const int* in_sizes, int n_in,
                              void* d_out, int out_size, void* d_ws, size_t ws_size,
                              hipStream_t stream)
{
    (void)in_sizes; (void)n_in; (void)out_size; (void)ws_size;
    const float* x    = (const float*)d_in[0];  // [8,512,64,64]
    const float* w    = (const float*)d_in[1];  // [8,512]
    const float* wt   = (const float*)d_in[2];  // [512,512,3,3]
    const float* bias = (const float*)d_in[3];  // [512]
    const float* aw   = (const float*)d_in[4];  // [512,512]
    const float* ab   = (const float*)d_in[5];  // [512]
    float* y = (float*)d_out;                   // [8,512,64,64]

    char* ws = (char*)d_ws;
    float*          style = (float*)ws;                          // 16 KB
    unsigned short* zpage = (unsigned short*)(ws + 16384);       // 256 B
    unsigned short* wr    = (unsigned short*)(ws + 32768);       // 4.5 MB
    unsigned short* xs    = (unsigned short*)(ws + 4751360);     // 32 MB

    prep_kernel<<<1536, 256, 0, stream>>>(w, aw, ab, style, zpage, wt, wr);
    modtrans_kernel<<<dim3(64, 8, 8), 256, 0, stream>>>(x, style, xs);
    conv_kernel<<<1024, 256, 0, stream>>>(xs, wr, bias, zpage, y);
}

// Round 3
// 252.693 us; speedup vs baseline: 1.1104x; 1.1104x over previous
//
#include <hip/hip_runtime.h>
#include <cstdint>
#include <cstddef>

// Problem constants
#define BATCH 8
#define CIN   512
#define COUT  512
#define RES   64
#define HW    4096      // 64*64
#define WDIM  512

typedef short bf16x8 __attribute__((ext_vector_type(8)));
typedef float f32x4  __attribute__((ext_vector_type(4)));
typedef unsigned short ushort8 __attribute__((ext_vector_type(8)));

typedef const __attribute__((address_space(1))) void* gas_ptr;
typedef __attribute__((address_space(3))) void*       las_ptr;

__device__ __forceinline__ unsigned short f2bf(float f) {
    unsigned int u = __float_as_uint(f);
    u += 0x7fffu + ((u >> 16) & 1u);   // round-to-nearest-even
    return (unsigned short)(u >> 16);
}

// ---------------------------------------------------------------------------
// Kernel 1 (fused prep): blocks 0..1023 compute style (+zero zpage);
// blocks 1024..1535 reorganize weights. The two roles are independent.
// style[b][ci] = sum_wd w[b][wd]*affine_w[ci][wd] + affine_b[ci]
// wr[tap][co][ci] = bf16(weight[co][ci][kh][kw]), tap = kh*3+kw
// ---------------------------------------------------------------------------
__global__ __launch_bounds__(256) void prep_kernel(
    const float* __restrict__ w, const float* __restrict__ aw,
    const float* __restrict__ ab, float* __restrict__ style,
    unsigned short* __restrict__ zpage,
    const float* __restrict__ wt, unsigned short* __restrict__ wr)
{
    __shared__ float buf[4608];
    int bid = blockIdx.x;
    int t = threadIdx.x;
    if (bid < 1024) {
        if (bid == 0 && t < 128) zpage[t] = 0;
        int wv = t >> 6, lane = t & 63;
        int idx = bid * 4 + wv;              // 0..4095
        int b = idx >> 9, ci = idx & 511;
        const float* wrow = w + b * WDIM;
        const float* arow = aw + (size_t)ci * WDIM;
        float s = 0.f;
#pragma unroll
        for (int i = 0; i < WDIM / 64; ++i) s += arow[lane + i * 64] * wrow[lane + i * 64];
#pragma unroll
        for (int off = 32; off; off >>= 1) s += __shfl_down(s, off);
        if (lane == 0) style[idx] = s + ab[ci];
    } else {
        int co = bid - 1024;
#pragma unroll
        for (int r = 0; r < 18; ++r) buf[r * 256 + t] = wt[(size_t)co * 4608 + r * 256 + t];
        __syncthreads();
#pragma unroll
        for (int r = 0; r < 18; ++r) {
            int idx = r * 256 + t;
            int tap = idx >> 9, ci = idx & 511;
            wr[(size_t)tap * (COUT * CIN) + co * CIN + ci] = f2bf(buf[ci * 9 + tap]);
        }
    }
}

// ---------------------------------------------------------------------------
// Kernel 2: xs[b][hw][ci] (bf16, NHWC) = bf16(x[b][ci][hw] * style[b][ci])
// 64x64 LDS-tiled transpose; 16B vectorized bf16 stores.
// ---------------------------------------------------------------------------
__global__ __launch_bounds__(256) void modtrans_kernel(
    const float* __restrict__ x, const float* __restrict__ style,
    unsigned short* __restrict__ xs)
{
    __shared__ float tile[64][65];
    int t = threadIdx.x;
    int hw0 = blockIdx.x * 64, ci0 = blockIdx.y * 64, b = blockIdx.z;
    int sub = t >> 6, lane = t & 63;
#pragma unroll
    for (int r = 0; r < 16; ++r) {
        int ci = r * 4 + sub;
        float s = style[b * CIN + ci0 + ci];
        tile[ci][lane] = x[((size_t)(b * CIN + ci0 + ci)) * HW + hw0 + lane] * s;
    }
    __syncthreads();
    int ci8 = (t & 7) * 8;
#pragma unroll
    for (int r = 0; r < 2; ++r) {
        int hw = r * 32 + (t >> 3);
        ushort8 v;
#pragma unroll
        for (int j = 0; j < 8; ++j) v[j] = f2bf(tile[ci8 + j][hw]);
        *(ushort8*)&xs[((size_t)b * HW + hw0 + hw) * CIN + ci0 + ci8] = v;
    }
}

// ---------------------------------------------------------------------------
// Kernel 3: implicit-GEMM conv, 256x256 C-tile (NEW this round).
// C-tile 256(co) x 256(hw = 4 image rows), 512 threads = 8 waves (2M x 4N),
// per wave 128co x 64hw -> acc 8x4 f32x4. 48 phases = 3 kh x 16 ci-chunks.
//
// Why: staging feed-BW is the wall (R1: +latency tolerance = no change;
// R2: locality shuffle at same traffic = worse). 256^2 tile stages 64 KB
// per phase for 4x the FLOPs of the old 128^2 tile -> staging bytes per
// FLOP halve (~25 -> ~12.5 TB/s L2-side demand at full MFMA pace).
// Grid = 2 cogrp x 16 hgrp x 8 b = 256 blocks = exactly 1/CU, single
// cohort (old kernel ran 2 sequential cohorts). LDS 129 KB (<=160).
//
// XCD map REVERTED to bid&7 = b: xs[b] = 4 MB = one XCD's L2 (R2 proved
// breaking this costs +92 MB HBM refetch); wr (4.5 MB) streams from L3.
//
// Schedule = R1's verified single-barrier pipeline: LDS double-buffered,
// { __syncthreads(); issue stage(p+1)->buf^1; compute(p) from buf }.
// Loads fly across a full compute phase (~3000 cyc) so the implicit
// vmcnt(0) at the barrier is nearly free. Race audit: stage(p+1)
// overwrites the buffer last READ in compute(p-1); every wave at the top
// of p has lgkm-drained those reads before its MFMAs -> barrier-separated.
//
// Bank-conflict swizzle (unchanged scheme): logical 16B chunk j of LDS
// row r lives at physical slot j ^ ((r>>1)&3). Staging permutes the
// per-lane GLOBAL source address (LDS dest stays base+lane*16); fragment
// reads apply the same xor. Read geometry identical to the 0-conflict
// 128^2 kernel.
// ---------------------------------------------------------------------------
__global__ __launch_bounds__(512, 2) void conv_kernel(
    const unsigned short* __restrict__ xs,   // [8][4096][512] bf16
    const unsigned short* __restrict__ wr,   // [9][512][512]  bf16
    const float* __restrict__ bias,
    const unsigned short* __restrict__ zpage,
    float* __restrict__ y)                   // [8][512][4096] f32
{
    __shared__ __align__(16) unsigned short As[2 * 3 * 256 * 32];  // 96 KB
    __shared__ __align__(16) unsigned short Bs[2 * 4 * 66 * 32];   // 33 KB
    constexpr int ABUF = 3 * 256 * 32;   // ushorts per A buffer
    constexpr int BBUF = 4 * 66 * 32;    // ushorts per B buffer

    const int t   = threadIdx.x;
    const int bid = blockIdx.x;
    // bid&7 = b keeps xs[b] (4 MB) resident in that XCD's L2.
    const int b    = bid & 7;
    const int hgrp = (bid >> 3) & 15;
    const int co0  = (bid >> 7) * 256;
    const int h0   = hgrp * 4;                // 4 image rows per block

    const int lane = t & 63;
    const int wv   = t >> 6;                  // 0..7
    const int wm   = (wv & 1) * 128;          // co offset within tile
    const int wn   = (wv >> 1) * 64;          // hw offset within tile
    const int r16  = lane & 15;
    const int quad = lane >> 4;

    // zero pad columns (w'=0 and w'=65) of all 4 dh rows in BOTH buffers:
    // 2 buf x 4 dh x 2 cols x 32 = 512 entries, one per thread.
    {
        int bufz = t >> 8;                 // 0 or 1
        int r = t & 255;
        int d = r >> 6, c = r & 63;
        int col = (c < 32) ? 0 : 65;
        Bs[bufz * BBUF + (d * 66 + col) * 32 + (c & 31)] = 0;
    }

    f32x4 acc[8][4];
#pragma unroll
    for (int mi = 0; mi < 8; ++mi)
#pragma unroll
        for (int ni = 0; ni < 4; ++ni)
            acc[mi][ni] = (f32x4){0.f, 0.f, 0.f, 0.f};

    const unsigned short* pA[6];
    const unsigned short* pB[2];
    int sB[2];

    // (Re)compute staging pointers for a kh (at its ch=0 position).
    auto setup = [&](int kh) {
#pragma unroll
        for (int L = 0; L < 6; ++L) {
            int lin = L * 512 + t;                 // 0..3071; phys row = lin>>2
            int tap = kh * 3 + (lin >> 10);        // 3 kw taps
            int q   = (lin >> 2) & 255;            // co row 0..255
            int c8  = ((lin & 3) ^ ((lin >> 3) & 3)) * 8;   // swizzled source chunk
            pA[L] = wr + (size_t)tap * (COUT * CIN) + (co0 + q) * CIN + c8;
        }
#pragma unroll
        for (int L = 0; L < 2; ++L) {
            int lin = L * 512 + t;                 // 0..1023
            int dh = lin >> 8, r8 = lin & 255;     // dh 0..3
            int wc = r8 >> 2;
            int rowp = dh * 66 + 1 + wc;           // physical LDS row
            int c8 = ((r8 & 3) ^ ((rowp >> 1) & 3)) * 8;
            int hp = h0 + dh + kh - 1;
            bool ok = (unsigned)hp < 64u;
            pB[L] = ok ? xs + ((size_t)b * HW + hp * 64 + wc) * CIN + c8 : zpage;
            sB[L] = ok ? 32 : 0;
        }
    };

    // Issue one phase's 8 global_load_lds into buffer `buf`; advance pointers.
    auto stage = [&](int buf) {
        const int ab = buf * ABUF, bb = buf * BBUF;
#pragma unroll
        for (int L = 0; L < 6; ++L) {
            int lin = L * 512 + t;
            __builtin_amdgcn_global_load_lds((gas_ptr)pA[L], (las_ptr)&As[ab + lin * 8], 16, 0, 0);
            pA[L] += 32;
        }
#pragma unroll
        for (int L = 0; L < 2; ++L) {
            int lin = L * 512 + t;
            int dh = lin >> 8, r8 = lin & 255;
            __builtin_amdgcn_global_load_lds((gas_ptr)pB[L],
                (las_ptr)&Bs[bb + (dh * 66 + 1) * 32 + r8 * 8], 16, 0, 0);
            pB[L] += sB[L];
        }
    };

    setup(0);
    stage(0);            // prologue: phase 0 in flight

    for (int p = 0; p < 48; ++p) {
        // Drains vmcnt(0)+lgkmcnt(0) then barrier: phase p's loads (flying
        // since early phase p-1, ~3000 cyc) are in LDS; all waves are done
        // reading buf^1 (their ds_reads were lgkm-drained before their MFMAs).
        __syncthreads();

        if (p < 47) {
            int pn = p + 1;
            if ((pn & 15) == 0) setup(pn >> 4);    // kh boundary (pn = 16, 32)
            stage(pn & 1);                         // flies across compute(p)
        }
        // pin the 8 VMEM issues ahead of the MFMA clusters
        __builtin_amdgcn_sched_barrier(0);

        const int ab = (p & 1) * ABUF, bb = (p & 1) * BBUF;
#pragma unroll
        for (int kw = 0; kw < 3; ++kw) {
            bf16x8 af[8], bfv[4];
#pragma unroll
            for (int mi = 0; mi < 8; ++mi) {
                int row = kw * 256 + wm + mi * 16 + r16;
                int ck  = quad ^ ((row >> 1) & 3);
                af[mi] = *(const bf16x8*)&As[ab + row * 32 + ck * 8];
            }
#pragma unroll
            for (int ni = 0; ni < 4; ++ni) {
                int n = wn + ni * 16 + r16;
                int dh = n >> 6, wc = n & 63;
                int row = dh * 66 + wc + kw;
                int ck  = quad ^ ((row >> 1) & 3);
                bfv[ni] = *(const bf16x8*)&Bs[bb + row * 32 + ck * 8];
            }
            __builtin_amdgcn_s_setprio(1);
#pragma unroll
            for (int mi = 0; mi < 8; ++mi)
#pragma unroll
                for (int ni = 0; ni < 4; ++ni)
                    acc[mi][ni] = __builtin_amdgcn_mfma_f32_16x16x32_bf16(
                        af[mi], bfv[ni], acc[mi][ni], 0, 0, 0);
            __builtin_amdgcn_s_setprio(0);
        }
    }

    // Epilogue: C/D layout col(n)=lane&15, row(m)=quad*4+reg
    const size_t hw0 = (size_t)hgrp * 256;
#pragma unroll
    for (int mi = 0; mi < 8; ++mi) {
#pragma unroll
        for (int r = 0; r < 4; ++r) {
            int m = co0 + wm + mi * 16 + quad * 4 + r;
            float bv = bias[m];
            size_t base = ((size_t)b * COUT + m) * HW + hw0;
#pragma unroll
            for (int ni = 0; ni < 4; ++ni) {
                int n = wn + ni * 16 + r16;
                y[base + n] = acc[mi][ni][r] + bv;
            }
        }
    }
}

// ---------------------------------------------------------------------------
extern "C" void kernel_launch(void* const* d_in, const int* in_sizes, int n_in,
                              void* d_out, int out_size, void* d_ws, size_t ws_size,
                              hipStream_t stream)
{
    (void)in_sizes; (void)n_in; (void)out_size; (void)ws_size;
    const float* x    = (const float*)d_in[0];  // [8,512,64,64]
    const float* w    = (const float*)d_in[1];  // [8,512]
    const float* wt   = (const float*)d_in[2];  // [512,512,3,3]
    const float* bias = (const float*)d_in[3];  // [512]
    const float* aw   = (const float*)d_in[4];  // [512,512]
    const float* ab   = (const float*)d_in[5];  // [512]
    float* y = (float*)d_out;                   // [8,512,64,64]

    char* ws = (char*)d_ws;
    float*          style = (float*)ws;                          // 16 KB
    unsigned short* zpage = (unsigned short*)(ws + 16384);       // 256 B
    unsigned short* wr    = (unsigned short*)(ws + 32768);       // 4.5 MB
    unsigned short* xs    = (unsigned short*)(ws + 4751360);     // 32 MB

    prep_kernel<<<1536, 256, 0, stream>>>(w, aw, ab, style, zpage, wt, wr);
    modtrans_kernel<<<dim3(64, 8, 8), 256, 0, stream>>>(x, style, xs);
    conv_kernel<<<256, 512, 0, stream>>>(xs, wr, bias, zpage, y);
}